// Round 13
// baseline (581.524 us; speedup 1.0000x reference)
//
#include <hip/hip_runtime.h>

#define PIX 4096
#define SCALE 0.25f

typedef _Float16 f16x8 __attribute__((ext_vector_type(8)));
typedef _Float16 f16x4 __attribute__((ext_vector_type(4)));
typedef float f32x4 __attribute__((ext_vector_type(4)));

__device__ inline void gload_lds16(const _Float16* g, _Float16* l) {
  __builtin_amdgcn_global_load_lds((const __attribute__((address_space(1))) void*)g,
                                   (__attribute__((address_space(3))) void*)l, 16, 0, 0);
}

// ---- fused prep: qk_w/proj_w -> fp16, build block-triangular Wbig fp16 ----
__global__ __launch_bounds__(256) void k_prep(const float* __restrict__ qk_w,
                                              const float* __restrict__ proj_w,
                                              const float* __restrict__ vs_w,
                                              _Float16* __restrict__ qkw_h,
                                              _Float16* __restrict__ pjw_h,
                                              _Float16* __restrict__ wbig_h) {
  int i = blockIdx.x * 256 + threadIdx.x;
  if (i < 131072) qkw_h[i] = (_Float16)qk_w[i];
  if (i < 262144) {
    pjw_h[i] = (_Float16)proj_w[i];
    int row = i >> 9, col = i & 511;
    int hi = row >> 6, d = row & 63, j = col >> 6, c = col & 63;
    wbig_h[i] = (j <= hi) ? (_Float16)vs_w[hi * 4096 + d * 64 + c] : (_Float16)0;
  }
}

// ---- x [b][512][4096] fp32 -> xh [b][4096][512] fp16 ---- grid (64,8,32)
__global__ __launch_bounds__(256) void k_xt(const float* __restrict__ x,
                                            _Float16* __restrict__ xh) {
  __shared__ float tile[64][65];
  int b = blockIdx.z, k0 = blockIdx.y * 64, p0 = blockIdx.x * 64;
  const float* xp = x + ((size_t)b * 512 + k0) * PIX + p0;
  _Float16* out = xh + (size_t)b * PIX * 512;
  int t = threadIdx.x;
  int r = t >> 4, c4 = (t & 15) << 2;
#pragma unroll
  for (int it = 0; it < 4; ++it) {
    float4 v = *(const float4*)&xp[(size_t)(r + it * 16) * PIX + c4];
    tile[r + it * 16][c4 + 0] = v.x; tile[r + it * 16][c4 + 1] = v.y;
    tile[r + it * 16][c4 + 2] = v.z; tile[r + it * 16][c4 + 3] = v.w;
  }
  __syncthreads();
  int pr = t >> 5, kk = (t & 31) << 1;
#pragma unroll
  for (int it = 0; it < 8; ++it) {
    int p = pr + it * 8;
    union { _Float16 h[2]; unsigned int u; } pk;
    pk.h[0] = (_Float16)tile[kk][p]; pk.h[1] = (_Float16)tile[kk + 1][p];
    *(unsigned int*)&out[(size_t)(p0 + p) * 512 + k0 + kk] = pk.u;
  }
}

// ==== MFMA GEMM, counted-vmcnt pipeline ====
// MODE 0: proj, M-tile 256, fp32 out. 2-slot depth-1, 64KB LDS (2 blocks/CU).
// MODE 1: V triangular, M-tile 128 + fused w-mix -> t fp16. 3-slot depth-2,
//         72KB LDS (still 2 blocks/CU); attnW fragments hoisted pre-loop.
// MODE 2: feat, M-tile 256: wm=0 -> fp16 q-feat (H2), wm=1 -> kh (H). 4-slot depth-3.
// NOTE: launch_bounds min-waves MUST stay 2 — 4 caps VGPR at 64 and spills the
// 128-reg accumulator to scratch (round-10 regression: 9x write amplification).
template<int MODE>
__global__ __launch_bounds__(512, 2)
void k_mg8(const _Float16* __restrict__ A,
           const _Float16* __restrict__ B,
           const float* __restrict__ bias,
           const _Float16* __restrict__ attn,
           float* C, _Float16* H, _Float16* H2, int nwg_m) {
  constexpr int MROWS = (MODE == 1) ? 128 : 256;
  constexpr int AH = MROWS * 32;          // A-tile halves per slot
  constexpr int SLOT = AH + 8192;         // slot stride (halves)
  constexpr int MI = MROWS / 32;          // per-wave m-frags
  constexpr int DEPTH = (MODE == 2) ? 3 : ((MODE == 1) ? 2 : 1);
  constexpr int NSLOT = (MODE == 2) ? 4 : ((MODE == 1) ? 3 : 2);
  constexpr int LDSH = (MODE == 2) ? 4 * SLOT : ((MODE == 1) ? 3 * SLOT : 32768);
  __shared__ __align__(16) _Float16 lds[LDSH];
  int nwg = gridDim.x;
  int id = blockIdx.x;
  int qq = nwg >> 3;
  id = (id & 7) * qq + (id >> 3);         // bijective XCD swizzle (nwg%8==0)
  int mb = id % nwg_m;
  int rest = id / nwg_m;
  int pb = rest & 15;
  int b  = rest >> 4;
  int m0 = mb * MROWS, p0 = pb * 256;
  int t = threadIdx.x, wid = t >> 6, lane = t & 63;
  int wm = wid >> 2, wn = wid & 3;
  int lr = lane & 15, q4 = lane >> 4;
  const _Float16* Ab = A + (size_t)m0 * 512;
  const _Float16* Bp = B + (size_t)b * 2097152 + (size_t)p0 * 512;

  int nt = (MODE == 1) ? ((m0 + 128) >> 6) : 8;
  int nsub = nt * 2;

  auto STAGE = [&](int g) {
    int slot = g % NSLOT;
    _Float16* dA = lds + slot * SLOT;
    _Float16* dB = dA + AH;
    size_t ks = (size_t)g * 32;
    if constexpr (MODE == 1) {
      int L = wid * 64 + lane;
      int row = L >> 2, sl = L & 3;
      int c = sl ^ ((row >> 1) & 3);
      gload_lds16(Ab + (size_t)row * 512 + ks + c * 8, dA + (size_t)(wid * 64) * 8);
    } else {
#pragma unroll
      for (int is = 0; is < 2; ++is) {
        int L = is * 512 + wid * 64 + lane;
        int row = L >> 2, sl = L & 3;
        int c = sl ^ ((row >> 1) & 3);
        gload_lds16(Ab + (size_t)row * 512 + ks + c * 8, dA + (size_t)(is * 512 + wid * 64) * 8);
      }
    }
#pragma unroll
    for (int is = 0; is < 2; ++is) {
      int L = is * 512 + wid * 64 + lane;
      int row = L >> 2, sl = L & 3;
      int c = sl ^ ((row >> 1) & 3);
      gload_lds16(Bp + (size_t)row * 512 + ks + c * 8, dB + (size_t)(is * 512 + wid * 64) * 8);
    }
  };

  // MODE 1: loop-invariant attnW B-fragments — load BEFORE the K-loop so the
  // global-load latency hides under the whole main loop (not the epilogue).
  int s_slab = pb * 4 + wn;
  f16x8 bfr[4][2];
  if constexpr (MODE == 1) {
    const _Float16* Ab2 = attn + ((size_t)b * 64 + s_slab) * 4096;
#pragma unroll
    for (int ni = 0; ni < 4; ++ni)
#pragma unroll
      for (int kk = 0; kk < 2; ++kk)
        bfr[ni][kk] = *(const f16x8*)&Ab2[(ni * 16 + lr) * 64 + q4 * 8 + kk * 32];
  }

  f32x4 acc[MI][4] = {};
#pragma unroll
  for (int g = 0; g < DEPTH; ++g) STAGE(g);
  for (int n = 0; n < nsub; ++n) {
    if (n + DEPTH < nsub) STAGE(n + DEPTH);
    int r = nsub - 1 - n; if (r > DEPTH) r = DEPTH;
    if constexpr (MODE == 1) {
      if (r >= 2)      asm volatile("s_waitcnt vmcnt(6)" ::: "memory");
      else if (r == 1) asm volatile("s_waitcnt vmcnt(3)" ::: "memory");
      else             asm volatile("s_waitcnt vmcnt(0)" ::: "memory");
    } else if constexpr (MODE == 0) {
      if (r >= 1) asm volatile("s_waitcnt vmcnt(4)" ::: "memory");
      else        asm volatile("s_waitcnt vmcnt(0)" ::: "memory");
    } else {
      if (r == 3)      asm volatile("s_waitcnt vmcnt(12)" ::: "memory");
      else if (r == 2) asm volatile("s_waitcnt vmcnt(8)" ::: "memory");
      else if (r == 1) asm volatile("s_waitcnt vmcnt(4)" ::: "memory");
      else             asm volatile("s_waitcnt vmcnt(0)" ::: "memory");
    }
    __builtin_amdgcn_s_barrier();
    const _Float16* A_s = lds + (n % NSLOT) * SLOT;
    const _Float16* B_s = A_s + AH;
    f16x8 af[MI], bf[4];
#pragma unroll
    for (int mi = 0; mi < MI; ++mi) {
      int row = wm * (MROWS / 2) + mi * 16 + lr;
      af[mi] = *(const f16x8*)&A_s[row * 32 + ((q4 ^ ((row >> 1) & 3)) << 3)];
    }
#pragma unroll
    for (int ni = 0; ni < 4; ++ni) {
      int row = wn * 64 + ni * 16 + lr;
      bf[ni] = *(const f16x8*)&B_s[row * 32 + ((q4 ^ ((row >> 1) & 3)) << 3)];
    }
    __builtin_amdgcn_s_setprio(1);
#pragma unroll
    for (int mi = 0; mi < MI; ++mi)
#pragma unroll
      for (int ni = 0; ni < 4; ++ni)
        acc[mi][ni] = __builtin_amdgcn_mfma_f32_16x16x32_f16(af[mi], bf[ni], acc[mi][ni], 0, 0, 0);
    __builtin_amdgcn_s_setprio(0);
    __builtin_amdgcn_s_barrier();
  }

  if (MODE == 0) {
#pragma unroll
    for (int mi = 0; mi < MI; ++mi)
#pragma unroll
      for (int rr = 0; rr < 4; ++rr) {
        int m = m0 + wm * 128 + mi * 16 + q4 * 4 + rr;
        float bi = bias[m];
        float* crow = C + ((size_t)b * 512 + m) * PIX + p0 + wn * 64;
#pragma unroll
        for (int ni = 0; ni < 4; ++ni)
          crow[ni * 16 + lr] = acc[mi][ni][rr] + bi;
      }
  }

  if (MODE == 1) {
    _Float16* Cs = lds + wid * 4096;               // per-wave 64x64 halves
#pragma unroll
    for (int mi = 0; mi < 4; ++mi)
#pragma unroll
      for (int ni = 0; ni < 4; ++ni)
#pragma unroll
        for (int rr = 0; rr < 4; ++rr) {
          int row = mi * 16 + q4 * 4 + rr;
          int col = ni * 16 + lr;
          Cs[row * 64 + ((((col >> 3) ^ (row & 7)) << 3) | (col & 7))] =
              (_Float16)(acc[mi][ni][rr] + bias[m0 + wm * 64 + row]);
        }
    f32x4 acc2[4][4] = {};
#pragma unroll
    for (int mi2 = 0; mi2 < 4; ++mi2)
#pragma unroll
      for (int kk = 0; kk < 2; ++kk) {
        int row = mi2 * 16 + lr;
        f16x8 afr = *(const f16x8*)&Cs[row * 64 + (((q4 + kk * 4) ^ (row & 7)) << 3)];
#pragma unroll
        for (int ni2 = 0; ni2 < 4; ++ni2)
          acc2[mi2][ni2] = __builtin_amdgcn_mfma_f32_16x16x32_f16(afr, bfr[ni2][kk], acc2[mi2][ni2], 0, 0, 0);
      }
#pragma unroll
    for (int mi2 = 0; mi2 < 4; ++mi2)
#pragma unroll
      for (int rr = 0; rr < 4; ++rr) {
        int m = m0 + wm * 64 + mi2 * 16 + q4 * 4 + rr;
        _Float16* crow = H + ((size_t)b * 512 + m) * PIX + p0 + wn * 64;
#pragma unroll
        for (int ni2 = 0; ni2 < 4; ++ni2)
          crow[ni2 * 16 + lr] = (_Float16)acc2[mi2][ni2][rr];
      }
  }

  if (MODE == 2) {
    if (wm == 0) {                                 // q-half -> fp16 feat
#pragma unroll
      for (int mi = 0; mi < MI; ++mi)
#pragma unroll
        for (int rr = 0; rr < 4; ++rr) {
          int m = mi * 16 + q4 * 4 + rr;           // 0..127
          float bi = bias[m];
          _Float16* crow = H2 + ((size_t)b * 128 + m) * PIX + p0 + wn * 64;
#pragma unroll
          for (int ni = 0; ni < 4; ++ni)
            crow[ni * 16 + lr] = (_Float16)(acc[mi][ni][rr] + bi);
        }
    } else {                                       // k-half -> kh fp16 [p][128c]
      _Float16* Ls = lds + (size_t)(wid - 4) * 16384;  // 64 x 136 halves per wave
#pragma unroll
      for (int mi = 0; mi < MI; ++mi)
#pragma unroll
        for (int ni = 0; ni < 4; ++ni)
#pragma unroll
          for (int rr = 0; rr < 4; ++rr) {
            int ch = mi * 16 + q4 * 4 + rr;        // 0..127
            Ls[(ni * 16 + lr) * 136 + ch] = (_Float16)(acc[mi][ni][rr] + bias[128 + ch]);
          }
      _Float16* khb = H + ((size_t)b * PIX + p0 + wn * 64) * 128;
#pragma unroll
      for (int it = 0; it < 16; ++it) {
        int chk = it * 64 + lane;
        int prow = chk >> 4, cc = (chk & 15) << 3;
        *(f16x8*)&khb[(size_t)prow * 128 + cc] = *(const f16x8*)&Ls[prow * 136 + cc];
      }
    }
  }
}

// ---- depthwise 5x5 SAME conv, fp16 in/out ---- grid (128, B)
__global__ __launch_bounds__(256) void k_dwconv(const _Float16* __restrict__ feat,
                                                const float* __restrict__ w,
                                                const float* __restrict__ bias,
                                                _Float16* __restrict__ qc) {
  __shared__ float tile[68][68];
  int c = blockIdx.x, b = blockIdx.y;
  const _Float16* in = feat + ((size_t)b * 128 + c) * PIX;
  float wreg[25];
#pragma unroll
  for (int i = 0; i < 25; ++i) wreg[i] = w[c * 25 + i];
  float bi = bias[c];
  int t = threadIdx.x;
  for (int idx = t; idx < 68 * 68; idx += 256) {
    int y = idx / 68, xx = idx - y * 68;
    int h = y - 2, ww = xx - 2;
    float v = 0.f;
    if (h >= 0 && h < 64 && ww >= 0 && ww < 64) v = (float)in[h * 64 + ww];
    tile[y][xx] = v;
  }
  __syncthreads();
  _Float16* out = qc + ((size_t)b * 128 + c) * PIX;
  int tx = (t & 15) << 2, ty = (t >> 4) << 2;
#pragma unroll
  for (int i = 0; i < 4; ++i) {
    f16x4 o;
#pragma unroll
    for (int j = 0; j < 4; ++j) {
      float s = bi;
#pragma unroll
      for (int dy = 0; dy < 5; ++dy)
#pragma unroll
        for (int dx = 0; dx < 5; ++dx)
          s += wreg[dy * 5 + dx] * tile[ty + i + dy][tx + j + dx];
      o[j] = (_Float16)s;
    }
    *(f16x4*)&out[(ty + i) * 64 + tx] = o;
  }
}

// ---- fp16 [128c][4096p] -> fp16 [4096p][128c] ---- grid (64,32)
__global__ __launch_bounds__(256) void k_qkt16(const _Float16* __restrict__ in,
                                               _Float16* __restrict__ out) {
  __shared__ __align__(16) _Float16 Ts[64 * 136];
  int p0 = blockIdx.x * 64, b = blockIdx.y;
  const _Float16* ip = in + (size_t)b * 128 * PIX;
  int t = threadIdx.x;
#pragma unroll
  for (int it = 0; it < 4; ++it) {
    int i4 = it * 256 + t;                 // 1024 chunks: 128c x 8
    int c = i4 >> 3, pc = (i4 & 7) << 3;
    f16x8 v = *(const f16x8*)&ip[(size_t)c * PIX + p0 + pc];
#pragma unroll
    for (int j = 0; j < 8; ++j) Ts[(pc + j) * 136 + c] = v[j];
  }
  __syncthreads();
  _Float16* op = out + (size_t)b * (PIX * 128) + (size_t)p0 * 128;
#pragma unroll
  for (int it = 0; it < 4; ++it) {
    int ch = it * 256 + t;
    int p = ch >> 4, cc = (ch & 15) << 3;
    *(f16x8*)&op[p * 128 + cc] = *(const f16x8*)&Ts[p * 136 + cc];
  }
}

// ---- MFMA attention scores+softmax -> fp16 attn [b][j][q][k] ---- grid (64,32,2)
__global__ __launch_bounds__(256) void k_mattn(const _Float16* __restrict__ qh,
                                               const _Float16* __restrict__ kh,
                                               const float* __restrict__ bias_w,
                                               const float* __restrict__ bias_h,
                                               _Float16* __restrict__ attnW,
                                               _Float16* __restrict__ attnH) {
  __shared__ __align__(16) _Float16 Qs[64 * 136];
  __shared__ __align__(16) _Float16 Ks[64 * 136];
  __shared__ float bl[64];
  int j = blockIdx.x, b = blockIdx.y, which = blockIdx.z;
  const float* bias = which ? bias_h : bias_w;
  _Float16* attn = which ? attnH : attnW;
  int t = threadIdx.x;
  if (t < 64) bl[t] = bias[t];
  const _Float16* qb = qh + (size_t)b * (PIX * 128);
  const _Float16* kb = kh + (size_t)b * (PIX * 128);
#pragma unroll
  for (int it = 0; it < 4; ++it) {
    int idx = it * 256 + t;
    int r = idx >> 4, cc = (idx & 15) << 3;
    size_t p = which ? (size_t)(j + 64 * r) : (size_t)(j * 64 + r);
    *(f16x8*)&Qs[r * 136 + cc] = *(const f16x8*)&qb[p * 128 + cc];
    *(f16x8*)&Ks[r * 136 + cc] = *(const f16x8*)&kb[p * 128 + cc];
  }
  __syncthreads();
  int wave = t >> 6, lane = t & 63;
  int lr = lane & 15, q4 = lane >> 4;
  f16x8 af[4];
#pragma unroll
  for (int kk = 0; kk < 4; ++kk)
    af[kk] = *(const f16x8*)&Qs[(wave * 16 + lr) * 136 + q4 * 8 + kk * 32];
  f32x4 acc[4] = {};
#pragma unroll
  for (int ni = 0; ni < 4; ++ni)
#pragma unroll
    for (int kk = 0; kk < 4; ++kk) {
      f16x8 bf = *(const f16x8*)&Ks[(ni * 16 + lr) * 136 + q4 * 8 + kk * 32];
      acc[ni] = __builtin_amdgcn_mfma_f32_16x16x32_f16(af[kk], bf, acc[ni], 0, 0, 0);
    }
  float ev[4][4], sm[4];
#pragma unroll
  for (int r = 0; r < 4; ++r) {
    int qrow = wave * 16 + q4 * 4 + r;
    float m = -1e30f;
#pragma unroll
    for (int ni = 0; ni < 4; ++ni) {
      int k = ni * 16 + lr;
      ev[ni][r] = acc[ni][r] * SCALE + bl[abs(qrow - k)];
      m = fmaxf(m, ev[ni][r]);
    }
    m = fmaxf(m, __shfl_xor(m, 1)); m = fmaxf(m, __shfl_xor(m, 2));
    m = fmaxf(m, __shfl_xor(m, 4)); m = fmaxf(m, __shfl_xor(m, 8));
    float s = 0.f;
#pragma unroll
    for (int ni = 0; ni < 4; ++ni) { ev[ni][r] = __expf(ev[ni][r] - m); s += ev[ni][r]; }
    s += __shfl_xor(s, 1); s += __shfl_xor(s, 2);
    s += __shfl_xor(s, 4); s += __shfl_xor(s, 8);
    sm[r] = 1.f / s;
  }
  _Float16* ab = attn + (((size_t)b * 64 + j) * 64) * 64;
#pragma unroll
  for (int r = 0; r < 4; ++r) {
    int qrow = wave * 16 + q4 * 4 + r;
#pragma unroll
    for (int ni = 0; ni < 4; ++ni)
      ab[qrow * 64 + ni * 16 + lr] = (_Float16)(ev[ni][r] * sm[r]);
  }
}

// ---- fused transpose + h-mix + relu (replaces k_t16 + k_hmix) ----
// ght[b][(h_out*64+w)][512ch] = relu(sum_h attnH[b,w][h_out,h] * t[b][ch][h*64+w])
__global__ __launch_bounds__(512, 2) void k_thmix(const _Float16* __restrict__ t,
                                                  const _Float16* __restrict__ attnH,
                                                  _Float16* __restrict__ ght) {
  __shared__ __align__(16) _Float16 T[16 * 32 * 72];  // [w16][c32][h 64 pad72]
  int nwg = gridDim.x;                  // 2048
  int p = blockIdx.x;
  int l = (p & 7) * (nwg >> 3) + (p >> 3);
  int wlo = l & 3, cht = (l >> 2) & 15, b = l >> 6;
  int w0 = wlo * 16;
  int tid = threadIdx.x, wid = tid >> 6, lane = tid & 63;
  int lr = lane & 15, q4 = lane >> 4;
  const _Float16* tb = t + ((size_t)b * 512 + cht * 32) * PIX + w0;
#pragma unroll
  for (int it = 0; it < 8; ++it) {
    int chunk = it * 512 + tid;          // 4096 chunks of 16B
    int c = chunk >> 7, rem = chunk & 127;
    int h = rem >> 1, wh = rem & 1;
    f16x8 v = *(const f16x8*)&tb[(size_t)c * PIX + h * 64 + wh * 8];
#pragma unroll
    for (int j = 0; j < 8; ++j)
      T[((wh * 8 + j) * 32 + c) * 72 + h] = v[j];
  }
  __syncthreads();
  _Float16* gb = ght + (size_t)b * PIX * 512 + cht * 32;
  for (int wi = 0; wi < 2; ++wi) {
    int w = wid * 2 + wi;                // local w 0..15
    const _Float16* Ab = attnH + ((size_t)b * 64 + w0 + w) * 4096;
    f16x8 bfr[4][2];
#pragma unroll
    for (int ni = 0; ni < 4; ++ni)
#pragma unroll
      for (int kk = 0; kk < 2; ++kk)
        bfr[ni][kk] = *(const f16x8*)&Ab[(ni * 16 + lr) * 64 + q4 * 8 + kk * 32];
    f32x4 acc[2][4] = {};
#pragma unroll
    for (int mf = 0; mf < 2; ++mf)
#pragma unroll
      for (int kk = 0; kk < 2; ++kk) {
        f16x8 af = *(const f16x8*)&T[(w * 32 + mf * 16 + lr) * 72 + q4 * 8 + kk * 32];
#pragma unroll
        for (int ni = 0; ni < 4; ++ni)
          acc[mf][ni] = __builtin_amdgcn_mfma_f32_16x16x32_f16(af, bfr[ni][kk], acc[mf][ni], 0, 0, 0);
      }
#pragma unroll
    for (int mf = 0; mf < 2; ++mf)
#pragma unroll
      for (int ni = 0; ni < 4; ++ni) {
        f16x4 o;
#pragma unroll
        for (int r = 0; r < 4; ++r) {
          float v = acc[mf][ni][r];
          o[r] = (_Float16)(v > 0.f ? v : 0.f);
        }
        *(f16x4*)&gb[((size_t)(ni * 16 + lr) * 64 + w0 + w) * 512 + mf * 16 + q4 * 4] = o;
      }
  }
}

extern "C" void kernel_launch(void* const* d_in, const int* in_sizes, int n_in,
                              void* d_out, int out_size, void* d_ws, size_t ws_size,
                              hipStream_t stream) {
  const float* x      = (const float*)d_in[0];
  const float* qk_w   = (const float*)d_in[1];
  const float* qk_b   = (const float*)d_in[2];
  const float* dws_w  = (const float*)d_in[3];
  const float* dws_b  = (const float*)d_in[4];
  const float* vs_w   = (const float*)d_in[5];
  const float* vs_b   = (const float*)d_in[6];
  const float* proj_w = (const float*)d_in[7];
  const float* proj_b = (const float*)d_in[8];
  const float* bias_h = (const float*)d_in[9];
  const float* bias_w = (const float*)d_in[10];

  float* ws = (float*)d_ws;
  float* dout = (float*)d_out;

  // ws layout (float units):
  _Float16* xh    = (_Float16*)ws;                 // [0,33.5M fl); reused as ght
  _Float16* ght   = xh;
  _Float16* attnW = (_Float16*)(ws + 67108864);
  _Float16* attnH = (_Float16*)(ws + 71303168);
  _Float16* qkw_h  = (_Float16*)(ws + 75497472);
  _Float16* wbig_h = (_Float16*)(ws + 75563008);
  _Float16* pjw_h  = (_Float16*)(ws + 75694080);

  // d_out phase scratch (all dead before proj writes):
  _Float16* feat_h = (_Float16*)dout;              // [0,8.4M fl)
  _Float16* qc_h   = (_Float16*)(dout + 8388608);  // [8.4M,16.8M fl)
  _Float16* qh     = (_Float16*)(dout + 16777216); // [16.8M,25.2M fl)
  _Float16* kh     = (_Float16*)(dout + 25165824); // [25.2M,33.6M fl)
  _Float16* Vh     = (_Float16*)(dout + 33554432); // t tiles [33.6M,67.1M fl)

  k_prep<<<1024, 256, 0, stream>>>(qk_w, proj_w, vs_w, qkw_h, pjw_h, wbig_h);
  k_xt<<<dim3(64, 8, 32), 256, 0, stream>>>(x, xh);
  // feat GEMM: q-half fp16 (feat_h) + kh fp16 fused
  k_mg8<2><<<512, 512, 0, stream>>>(qkw_h, xh, qk_b, nullptr, nullptr, kh, feat_h, 1);
  k_dwconv<<<dim3(128, 32), 256, 0, stream>>>(feat_h, dws_w, dws_b, qc_h);
  k_qkt16<<<dim3(64, 32), 256, 0, stream>>>(qc_h, qh);
  k_mattn<<<dim3(64, 32, 2), 256, 0, stream>>>(qh, kh, bias_w, bias_h, attnW, attnH);
  // V GEMM (triangular, M-tile 128, depth-2) + fused w-mix -> t (contiguous)
  k_mg8<1><<<2048, 512, 0, stream>>>(wbig_h, xh, vs_b, attnW, nullptr, Vh, nullptr, 4);
  // ght = relu(attnH ⊙ transpose(t)), fused
  k_thmix<<<2048, 512, 0, stream>>>(Vh, attnH, ght);
  // out = proj_w @ g + proj_b (fp32)
  k_mg8<0><<<1024, 512, 0, stream>>>(pjw_h, ght, proj_b, nullptr, dout, nullptr, nullptr, 2);
}

// Round 14
// 549.508 us; speedup vs baseline: 1.0583x; 1.0583x over previous
//
#include <hip/hip_runtime.h>

#define PIX 4096
#define SCALE 0.25f

typedef _Float16 f16x8 __attribute__((ext_vector_type(8)));
typedef _Float16 f16x4 __attribute__((ext_vector_type(4)));
typedef float f32x4 __attribute__((ext_vector_type(4)));

__device__ inline void gload_lds16(const _Float16* g, _Float16* l) {
  __builtin_amdgcn_global_load_lds((const __attribute__((address_space(1))) void*)g,
                                   (__attribute__((address_space(3))) void*)l, 16, 0, 0);
}

// ---- fused prep: qk_w/proj_w -> fp16, build block-triangular Wbig fp16 ----
__global__ __launch_bounds__(256) void k_prep(const float* __restrict__ qk_w,
                                              const float* __restrict__ proj_w,
                                              const float* __restrict__ vs_w,
                                              _Float16* __restrict__ qkw_h,
                                              _Float16* __restrict__ pjw_h,
                                              _Float16* __restrict__ wbig_h) {
  int i = blockIdx.x * 256 + threadIdx.x;
  if (i < 131072) qkw_h[i] = (_Float16)qk_w[i];
  if (i < 262144) {
    pjw_h[i] = (_Float16)proj_w[i];
    int row = i >> 9, col = i & 511;
    int hi = row >> 6, d = row & 63, j = col >> 6, c = col & 63;
    wbig_h[i] = (j <= hi) ? (_Float16)vs_w[hi * 4096 + d * 64 + c] : (_Float16)0;
  }
}

// ---- x [b][512][4096] fp32 -> xh [b][4096][512] fp16 ---- grid (64,8,32)
__global__ __launch_bounds__(256) void k_xt(const float* __restrict__ x,
                                            _Float16* __restrict__ xh) {
  __shared__ float tile[64][65];
  int b = blockIdx.z, k0 = blockIdx.y * 64, p0 = blockIdx.x * 64;
  const float* xp = x + ((size_t)b * 512 + k0) * PIX + p0;
  _Float16* out = xh + (size_t)b * PIX * 512;
  int t = threadIdx.x;
  int r = t >> 4, c4 = (t & 15) << 2;
#pragma unroll
  for (int it = 0; it < 4; ++it) {
    float4 v = *(const float4*)&xp[(size_t)(r + it * 16) * PIX + c4];
    tile[r + it * 16][c4 + 0] = v.x; tile[r + it * 16][c4 + 1] = v.y;
    tile[r + it * 16][c4 + 2] = v.z; tile[r + it * 16][c4 + 3] = v.w;
  }
  __syncthreads();
  int pr = t >> 5, kk = (t & 31) << 1;
#pragma unroll
  for (int it = 0; it < 8; ++it) {
    int p = pr + it * 8;
    union { _Float16 h[2]; unsigned int u; } pk;
    pk.h[0] = (_Float16)tile[kk][p]; pk.h[1] = (_Float16)tile[kk + 1][p];
    *(unsigned int*)&out[(size_t)(p0 + p) * 512 + k0 + kk] = pk.u;
  }
}

// ==== MFMA GEMM, counted-vmcnt pipeline ====
// MODE 0: proj, M-tile 256, fp32 out. 2-slot depth-1, 64KB LDS (2 blocks/CU).
// MODE 1: V triangular, M-tile 128 + fused w-mix -> t fp16. 2-slot depth-1.
//   (round-13 ERRATUM: depth-2 + hoisted attnW fragments regressed 551->581 —
//    +32 live VGPRs across the K-loop; epilogue-loading bfr is faster.)
// MODE 2: feat, M-tile 256: wm=0 -> fp16 q-feat (H2), wm=1 -> kh (H). 4-slot depth-3.
// NOTE: launch_bounds min-waves MUST stay 2 — 4 caps VGPR at 64 and spills the
// 128-reg accumulator to scratch (round-10 regression: 9x write amplification).
template<int MODE>
__global__ __launch_bounds__(512, 2)
void k_mg8(const _Float16* __restrict__ A,
           const _Float16* __restrict__ B,
           const float* __restrict__ bias,
           const _Float16* __restrict__ attn,
           float* C, _Float16* H, _Float16* H2, int nwg_m) {
  constexpr int MROWS = (MODE == 1) ? 128 : 256;
  constexpr int AH = MROWS * 32;          // A-tile halves per slot
  constexpr int SLOT = AH + 8192;         // slot stride (halves)
  constexpr int MI = MROWS / 32;          // per-wave m-frags
  constexpr int DEPTH = (MODE == 2) ? 3 : 1;
  constexpr int NSLOT = (MODE == 2) ? 4 : 2;
  constexpr int LDSH = (MODE == 2) ? NSLOT * SLOT : 32768;  // 128KB / 64KB
  __shared__ __align__(16) _Float16 lds[LDSH];
  int nwg = gridDim.x;
  int id = blockIdx.x;
  int qq = nwg >> 3;
  id = (id & 7) * qq + (id >> 3);         // bijective XCD swizzle (nwg%8==0)
  int mb = id % nwg_m;
  int rest = id / nwg_m;
  int pb = rest & 15;
  int b  = rest >> 4;
  int m0 = mb * MROWS, p0 = pb * 256;
  int t = threadIdx.x, wid = t >> 6, lane = t & 63;
  int wm = wid >> 2, wn = wid & 3;
  int lr = lane & 15, q4 = lane >> 4;
  const _Float16* Ab = A + (size_t)m0 * 512;
  const _Float16* Bp = B + (size_t)b * 2097152 + (size_t)p0 * 512;

  int nt = (MODE == 1) ? ((m0 + 128) >> 6) : 8;
  int nsub = nt * 2;

  auto STAGE = [&](int g) {
    int slot = g % NSLOT;
    _Float16* dA = lds + slot * SLOT;
    _Float16* dB = dA + AH;
    size_t ks = (size_t)g * 32;
    if constexpr (MODE == 1) {
      int L = wid * 64 + lane;
      int row = L >> 2, sl = L & 3;
      int c = sl ^ ((row >> 1) & 3);
      gload_lds16(Ab + (size_t)row * 512 + ks + c * 8, dA + (size_t)(wid * 64) * 8);
    } else {
#pragma unroll
      for (int is = 0; is < 2; ++is) {
        int L = is * 512 + wid * 64 + lane;
        int row = L >> 2, sl = L & 3;
        int c = sl ^ ((row >> 1) & 3);
        gload_lds16(Ab + (size_t)row * 512 + ks + c * 8, dA + (size_t)(is * 512 + wid * 64) * 8);
      }
    }
#pragma unroll
    for (int is = 0; is < 2; ++is) {
      int L = is * 512 + wid * 64 + lane;
      int row = L >> 2, sl = L & 3;
      int c = sl ^ ((row >> 1) & 3);
      gload_lds16(Bp + (size_t)row * 512 + ks + c * 8, dB + (size_t)(is * 512 + wid * 64) * 8);
    }
  };

  f32x4 acc[MI][4] = {};
  if constexpr (DEPTH == 3) { STAGE(0); STAGE(1); STAGE(2); }
  else STAGE(0);
  for (int n = 0; n < nsub; ++n) {
    if (n + DEPTH < nsub) STAGE(n + DEPTH);
    int r = nsub - 1 - n; if (r > DEPTH) r = DEPTH;
    if constexpr (MODE == 1) {
      if (r >= 1) asm volatile("s_waitcnt vmcnt(3)" ::: "memory");
      else        asm volatile("s_waitcnt vmcnt(0)" ::: "memory");
    } else if constexpr (MODE == 0) {
      if (r >= 1) asm volatile("s_waitcnt vmcnt(4)" ::: "memory");
      else        asm volatile("s_waitcnt vmcnt(0)" ::: "memory");
    } else {
      if (r == 3)      asm volatile("s_waitcnt vmcnt(12)" ::: "memory");
      else if (r == 2) asm volatile("s_waitcnt vmcnt(8)" ::: "memory");
      else if (r == 1) asm volatile("s_waitcnt vmcnt(4)" ::: "memory");
      else             asm volatile("s_waitcnt vmcnt(0)" ::: "memory");
    }
    __builtin_amdgcn_s_barrier();
    const _Float16* A_s = lds + (n % NSLOT) * SLOT;
    const _Float16* B_s = A_s + AH;
    f16x8 af[MI], bf[4];
#pragma unroll
    for (int mi = 0; mi < MI; ++mi) {
      int row = wm * (MROWS / 2) + mi * 16 + lr;
      af[mi] = *(const f16x8*)&A_s[row * 32 + ((q4 ^ ((row >> 1) & 3)) << 3)];
    }
#pragma unroll
    for (int ni = 0; ni < 4; ++ni) {
      int row = wn * 64 + ni * 16 + lr;
      bf[ni] = *(const f16x8*)&B_s[row * 32 + ((q4 ^ ((row >> 1) & 3)) << 3)];
    }
    __builtin_amdgcn_s_setprio(1);
#pragma unroll
    for (int mi = 0; mi < MI; ++mi)
#pragma unroll
      for (int ni = 0; ni < 4; ++ni)
        acc[mi][ni] = __builtin_amdgcn_mfma_f32_16x16x32_f16(af[mi], bf[ni], acc[mi][ni], 0, 0, 0);
    __builtin_amdgcn_s_setprio(0);
    __builtin_amdgcn_s_barrier();
  }

  if (MODE == 0) {
#pragma unroll
    for (int mi = 0; mi < MI; ++mi)
#pragma unroll
      for (int rr = 0; rr < 4; ++rr) {
        int m = m0 + wm * 128 + mi * 16 + q4 * 4 + rr;
        float bi = bias[m];
        float* crow = C + ((size_t)b * 512 + m) * PIX + p0 + wn * 64;
#pragma unroll
        for (int ni = 0; ni < 4; ++ni)
          crow[ni * 16 + lr] = acc[mi][ni][rr] + bi;
      }
  }

  if (MODE == 1) {
    _Float16* Cs = lds + wid * 4096;               // per-wave 64x64 halves
#pragma unroll
    for (int mi = 0; mi < 4; ++mi)
#pragma unroll
      for (int ni = 0; ni < 4; ++ni)
#pragma unroll
        for (int rr = 0; rr < 4; ++rr) {
          int row = mi * 16 + q4 * 4 + rr;
          int col = ni * 16 + lr;
          Cs[row * 64 + ((((col >> 3) ^ (row & 7)) << 3) | (col & 7))] =
              (_Float16)(acc[mi][ni][rr] + bias[m0 + wm * 64 + row]);
        }
    int s = pb * 4 + wn;                           // h-slab of this wave
    const _Float16* Ab2 = attn + ((size_t)b * 64 + s) * 4096;
    f16x8 bfr[4][2];
#pragma unroll
    for (int ni = 0; ni < 4; ++ni)
#pragma unroll
      for (int kk = 0; kk < 2; ++kk)
        bfr[ni][kk] = *(const f16x8*)&Ab2[(ni * 16 + lr) * 64 + q4 * 8 + kk * 32];
    f32x4 acc2[4][4] = {};
#pragma unroll
    for (int mi2 = 0; mi2 < 4; ++mi2)
#pragma unroll
      for (int kk = 0; kk < 2; ++kk) {
        int row = mi2 * 16 + lr;
        f16x8 afr = *(const f16x8*)&Cs[row * 64 + (((q4 + kk * 4) ^ (row & 7)) << 3)];
#pragma unroll
        for (int ni2 = 0; ni2 < 4; ++ni2)
          acc2[mi2][ni2] = __builtin_amdgcn_mfma_f32_16x16x32_f16(afr, bfr[ni2][kk], acc2[mi2][ni2], 0, 0, 0);
      }
#pragma unroll
    for (int mi2 = 0; mi2 < 4; ++mi2)
#pragma unroll
      for (int rr = 0; rr < 4; ++rr) {
        int m = m0 + wm * 64 + mi2 * 16 + q4 * 4 + rr;
        _Float16* crow = H + ((size_t)b * 512 + m) * PIX + p0 + wn * 64;
#pragma unroll
        for (int ni2 = 0; ni2 < 4; ++ni2)
          crow[ni2 * 16 + lr] = (_Float16)acc2[mi2][ni2][rr];
      }
  }

  if (MODE == 2) {
    if (wm == 0) {                                 // q-half -> fp16 feat
#pragma unroll
      for (int mi = 0; mi < MI; ++mi)
#pragma unroll
        for (int rr = 0; rr < 4; ++rr) {
          int m = mi * 16 + q4 * 4 + rr;           // 0..127
          float bi = bias[m];
          _Float16* crow = H2 + ((size_t)b * 128 + m) * PIX + p0 + wn * 64;
#pragma unroll
          for (int ni = 0; ni < 4; ++ni)
            crow[ni * 16 + lr] = (_Float16)(acc[mi][ni][rr] + bi);
        }
    } else {                                       // k-half -> kh fp16 [p][128c]
      _Float16* Ls = lds + (size_t)(wid - 4) * 16384;  // 64 x 136 halves per wave
#pragma unroll
      for (int mi = 0; mi < MI; ++mi)
#pragma unroll
        for (int ni = 0; ni < 4; ++ni)
#pragma unroll
          for (int rr = 0; rr < 4; ++rr) {
            int ch = mi * 16 + q4 * 4 + rr;        // 0..127
            Ls[(ni * 16 + lr) * 136 + ch] = (_Float16)(acc[mi][ni][rr] + bias[128 + ch]);
          }
      _Float16* khb = H + ((size_t)b * PIX + p0 + wn * 64) * 128;
#pragma unroll
      for (int it = 0; it < 16; ++it) {
        int chk = it * 64 + lane;
        int prow = chk >> 4, cc = (chk & 15) << 3;
        *(f16x8*)&khb[(size_t)prow * 128 + cc] = *(const f16x8*)&Ls[prow * 136 + cc];
      }
    }
  }
}

// ---- depthwise 5x5 SAME conv, fp16 in/out ---- grid (128, B)
__global__ __launch_bounds__(256) void k_dwconv(const _Float16* __restrict__ feat,
                                                const float* __restrict__ w,
                                                const float* __restrict__ bias,
                                                _Float16* __restrict__ qc) {
  __shared__ float tile[68][68];
  int c = blockIdx.x, b = blockIdx.y;
  const _Float16* in = feat + ((size_t)b * 128 + c) * PIX;
  float wreg[25];
#pragma unroll
  for (int i = 0; i < 25; ++i) wreg[i] = w[c * 25 + i];
  float bi = bias[c];
  int t = threadIdx.x;
  for (int idx = t; idx < 68 * 68; idx += 256) {
    int y = idx / 68, xx = idx - y * 68;
    int h = y - 2, ww = xx - 2;
    float v = 0.f;
    if (h >= 0 && h < 64 && ww >= 0 && ww < 64) v = (float)in[h * 64 + ww];
    tile[y][xx] = v;
  }
  __syncthreads();
  _Float16* out = qc + ((size_t)b * 128 + c) * PIX;
  int tx = (t & 15) << 2, ty = (t >> 4) << 2;
#pragma unroll
  for (int i = 0; i < 4; ++i) {
    f16x4 o;
#pragma unroll
    for (int j = 0; j < 4; ++j) {
      float s = bi;
#pragma unroll
      for (int dy = 0; dy < 5; ++dy)
#pragma unroll
        for (int dx = 0; dx < 5; ++dx)
          s += wreg[dy * 5 + dx] * tile[ty + i + dy][tx + j + dx];
      o[j] = (_Float16)s;
    }
    *(f16x4*)&out[(ty + i) * 64 + tx] = o;
  }
}

// ---- fp16 [128c][4096p] -> fp16 [4096p][128c] ---- grid (64,32)
__global__ __launch_bounds__(256) void k_qkt16(const _Float16* __restrict__ in,
                                               _Float16* __restrict__ out) {
  __shared__ __align__(16) _Float16 Ts[64 * 136];
  int p0 = blockIdx.x * 64, b = blockIdx.y;
  const _Float16* ip = in + (size_t)b * 128 * PIX;
  int t = threadIdx.x;
#pragma unroll
  for (int it = 0; it < 4; ++it) {
    int i4 = it * 256 + t;                 // 1024 chunks: 128c x 8
    int c = i4 >> 3, pc = (i4 & 7) << 3;
    f16x8 v = *(const f16x8*)&ip[(size_t)c * PIX + p0 + pc];
#pragma unroll
    for (int j = 0; j < 8; ++j) Ts[(pc + j) * 136 + c] = v[j];
  }
  __syncthreads();
  _Float16* op = out + (size_t)b * (PIX * 128) + (size_t)p0 * 128;
#pragma unroll
  for (int it = 0; it < 4; ++it) {
    int ch = it * 256 + t;
    int p = ch >> 4, cc = (ch & 15) << 3;
    *(f16x8*)&op[p * 128 + cc] = *(const f16x8*)&Ts[p * 136 + cc];
  }
}

// ---- MFMA attention scores+softmax -> fp16 attn [b][j][q][k] ---- grid (64,32,2)
__global__ __launch_bounds__(256) void k_mattn(const _Float16* __restrict__ qh,
                                               const _Float16* __restrict__ kh,
                                               const float* __restrict__ bias_w,
                                               const float* __restrict__ bias_h,
                                               _Float16* __restrict__ attnW,
                                               _Float16* __restrict__ attnH) {
  __shared__ __align__(16) _Float16 Qs[64 * 136];
  __shared__ __align__(16) _Float16 Ks[64 * 136];
  __shared__ float bl[64];
  int j = blockIdx.x, b = blockIdx.y, which = blockIdx.z;
  const float* bias = which ? bias_h : bias_w;
  _Float16* attn = which ? attnH : attnW;
  int t = threadIdx.x;
  if (t < 64) bl[t] = bias[t];
  const _Float16* qb = qh + (size_t)b * (PIX * 128);
  const _Float16* kb = kh + (size_t)b * (PIX * 128);
#pragma unroll
  for (int it = 0; it < 4; ++it) {
    int idx = it * 256 + t;
    int r = idx >> 4, cc = (idx & 15) << 3;
    size_t p = which ? (size_t)(j + 64 * r) : (size_t)(j * 64 + r);
    *(f16x8*)&Qs[r * 136 + cc] = *(const f16x8*)&qb[p * 128 + cc];
    *(f16x8*)&Ks[r * 136 + cc] = *(const f16x8*)&kb[p * 128 + cc];
  }
  __syncthreads();
  int wave = t >> 6, lane = t & 63;
  int lr = lane & 15, q4 = lane >> 4;
  f16x8 af[4];
#pragma unroll
  for (int kk = 0; kk < 4; ++kk)
    af[kk] = *(const f16x8*)&Qs[(wave * 16 + lr) * 136 + q4 * 8 + kk * 32];
  f32x4 acc[4] = {};
#pragma unroll
  for (int ni = 0; ni < 4; ++ni)
#pragma unroll
    for (int kk = 0; kk < 4; ++kk) {
      f16x8 bf = *(const f16x8*)&Ks[(ni * 16 + lr) * 136 + q4 * 8 + kk * 32];
      acc[ni] = __builtin_amdgcn_mfma_f32_16x16x32_f16(af[kk], bf, acc[ni], 0, 0, 0);
    }
  float ev[4][4], sm[4];
#pragma unroll
  for (int r = 0; r < 4; ++r) {
    int qrow = wave * 16 + q4 * 4 + r;
    float m = -1e30f;
#pragma unroll
    for (int ni = 0; ni < 4; ++ni) {
      int k = ni * 16 + lr;
      ev[ni][r] = acc[ni][r] * SCALE + bl[abs(qrow - k)];
      m = fmaxf(m, ev[ni][r]);
    }
    m = fmaxf(m, __shfl_xor(m, 1)); m = fmaxf(m, __shfl_xor(m, 2));
    m = fmaxf(m, __shfl_xor(m, 4)); m = fmaxf(m, __shfl_xor(m, 8));
    float s = 0.f;
#pragma unroll
    for (int ni = 0; ni < 4; ++ni) { ev[ni][r] = __expf(ev[ni][r] - m); s += ev[ni][r]; }
    s += __shfl_xor(s, 1); s += __shfl_xor(s, 2);
    s += __shfl_xor(s, 4); s += __shfl_xor(s, 8);
    sm[r] = 1.f / s;
  }
  _Float16* ab = attn + (((size_t)b * 64 + j) * 64) * 64;
#pragma unroll
  for (int r = 0; r < 4; ++r) {
    int qrow = wave * 16 + q4 * 4 + r;
#pragma unroll
    for (int ni = 0; ni < 4; ++ni)
      ab[qrow * 64 + ni * 16 + lr] = (_Float16)(ev[ni][r] * sm[r]);
  }
}

// ---- fused transpose + h-mix + relu (replaces k_t16 + k_hmix) ----
// ght[b][(h_out*64+w)][512ch] = relu(sum_h attnH[b,w][h_out,h] * t[b][ch][h*64+w])
__global__ __launch_bounds__(512, 2) void k_thmix(const _Float16* __restrict__ t,
                                                  const _Float16* __restrict__ attnH,
                                                  _Float16* __restrict__ ght) {
  __shared__ __align__(16) _Float16 T[16 * 32 * 72];  // [w16][c32][h 64 pad72]
  int nwg = gridDim.x;                  // 2048
  int p = blockIdx.x;
  int l = (p & 7) * (nwg >> 3) + (p >> 3);
  int wlo = l & 3, cht = (l >> 2) & 15, b = l >> 6;
  int w0 = wlo * 16;
  int tid = threadIdx.x, wid = tid >> 6, lane = tid & 63;
  int lr = lane & 15, q4 = lane >> 4;
  const _Float16* tb = t + ((size_t)b * 512 + cht * 32) * PIX + w0;
#pragma unroll
  for (int it = 0; it < 8; ++it) {
    int chunk = it * 512 + tid;          // 4096 chunks of 16B
    int c = chunk >> 7, rem = chunk & 127;
    int h = rem >> 1, wh = rem & 1;
    f16x8 v = *(const f16x8*)&tb[(size_t)c * PIX + h * 64 + wh * 8];
#pragma unroll
    for (int j = 0; j < 8; ++j)
      T[((wh * 8 + j) * 32 + c) * 72 + h] = v[j];
  }
  __syncthreads();
  _Float16* gb = ght + (size_t)b * PIX * 512 + cht * 32;
  for (int wi = 0; wi < 2; ++wi) {
    int w = wid * 2 + wi;                // local w 0..15
    const _Float16* Ab = attnH + ((size_t)b * 64 + w0 + w) * 4096;
    f16x8 bfr[4][2];
#pragma unroll
    for (int ni = 0; ni < 4; ++ni)
#pragma unroll
      for (int kk = 0; kk < 2; ++kk)
        bfr[ni][kk] = *(const f16x8*)&Ab[(ni * 16 + lr) * 64 + q4 * 8 + kk * 32];
    f32x4 acc[2][4] = {};
#pragma unroll
    for (int mf = 0; mf < 2; ++mf)
#pragma unroll
      for (int kk = 0; kk < 2; ++kk) {
        f16x8 af = *(const f16x8*)&T[(w * 32 + mf * 16 + lr) * 72 + q4 * 8 + kk * 32];
#pragma unroll
        for (int ni = 0; ni < 4; ++ni)
          acc[mf][ni] = __builtin_amdgcn_mfma_f32_16x16x32_f16(af, bfr[ni][kk], acc[mf][ni], 0, 0, 0);
      }
#pragma unroll
    for (int mf = 0; mf < 2; ++mf)
#pragma unroll
      for (int ni = 0; ni < 4; ++ni) {
        f16x4 o;
#pragma unroll
        for (int r = 0; r < 4; ++r) {
          float v = acc[mf][ni][r];
          o[r] = (_Float16)(v > 0.f ? v : 0.f);
        }
        *(f16x4*)&gb[((size_t)(ni * 16 + lr) * 64 + w0 + w) * 512 + mf * 16 + q4 * 4] = o;
      }
  }
}

extern "C" void kernel_launch(void* const* d_in, const int* in_sizes, int n_in,
                              void* d_out, int out_size, void* d_ws, size_t ws_size,
                              hipStream_t stream) {
  const float* x      = (const float*)d_in[0];
  const float* qk_w   = (const float*)d_in[1];
  const float* qk_b   = (const float*)d_in[2];
  const float* dws_w  = (const float*)d_in[3];
  const float* dws_b  = (const float*)d_in[4];
  const float* vs_w   = (const float*)d_in[5];
  const float* vs_b   = (const float*)d_in[6];
  const float* proj_w = (const float*)d_in[7];
  const float* proj_b = (const float*)d_in[8];
  const float* bias_h = (const float*)d_in[9];
  const float* bias_w = (const float*)d_in[10];

  float* ws = (float*)d_ws;
  float* dout = (float*)d_out;

  // ws layout (float units):
  _Float16* xh    = (_Float16*)ws;                 // [0,33.5M fl); reused as ght
  _Float16* ght   = xh;
  _Float16* attnW = (_Float16*)(ws + 67108864);
  _Float16* attnH = (_Float16*)(ws + 71303168);
  _Float16* qkw_h  = (_Float16*)(ws + 75497472);
  _Float16* wbig_h = (_Float16*)(ws + 75563008);
  _Float16* pjw_h  = (_Float16*)(ws + 75694080);

  // d_out phase scratch (all dead before proj writes):
  _Float16* feat_h = (_Float16*)dout;              // [0,8.4M fl)
  _Float16* qc_h   = (_Float16*)(dout + 8388608);  // [8.4M,16.8M fl)
  _Float16* qh     = (_Float16*)(dout + 16777216); // [16.8M,25.2M fl)
  _Float16* kh     = (_Float16*)(dout + 25165824); // [25.2M,33.6M fl)
  _Float16* Vh     = (_Float16*)(dout + 33554432); // t tiles [33.6M,67.1M fl)

  k_prep<<<1024, 256, 0, stream>>>(qk_w, proj_w, vs_w, qkw_h, pjw_h, wbig_h);
  k_xt<<<dim3(64, 8, 32), 256, 0, stream>>>(x, xh);
  // feat GEMM: q-half fp16 (feat_h) + kh fp16 fused
  k_mg8<2><<<512, 512, 0, stream>>>(qkw_h, xh, qk_b, nullptr, nullptr, kh, feat_h, 1);
  k_dwconv<<<dim3(128, 32), 256, 0, stream>>>(feat_h, dws_w, dws_b, qc_h);
  k_qkt16<<<dim3(64, 32), 256, 0, stream>>>(qc_h, qh);
  k_mattn<<<dim3(64, 32, 2), 256, 0, stream>>>(qh, kh, bias_w, bias_h, attnW, attnH);
  // V GEMM (triangular, M-tile 128, depth-1) + fused w-mix -> t (contiguous)
  k_mg8<1><<<2048, 512, 0, stream>>>(wbig_h, xh, vs_b, attnW, nullptr, Vh, nullptr, 4);
  // ght = relu(attnH ⊙ transpose(t)), fused
  k_thmix<<<2048, 512, 0, stream>>>(Vh, attnH, ght);
  // out = proj_w @ g + proj_b (fp32)
  k_mg8<0><<<1024, 512, 0, stream>>>(pjw_h, ght, proj_b, nullptr, dout, nullptr, nullptr, 2);
}